// Round 7
// baseline (182.991 us; speedup 1.0000x reference)
//
#include <hip/hip_runtime.h>
#include <stdint.h>

#define S_LEN 2048
#define EMBED 1024
#define HEADS 16
#define HD 64
#define M_ROWS 4096      // B*S
#define N_QKV 3072
#define KDIM 1024
#define SP 2336          // padded vT row length: 128 + 2048 + 160
#define CLP2 200         // qkv C-tile LDS col stride (u16)

typedef __attribute__((ext_vector_type(8))) short short8;
typedef __attribute__((ext_vector_type(4))) float f32x4;

__device__ __forceinline__ unsigned short f2bf(float f) {
  union { float f; uint32_t u; } c; c.f = f;
  uint32_t u = c.u;
  u += 0x7fffu + ((u >> 16) & 1u);  // round-to-nearest-even
  return (unsigned short)(u >> 16);
}

// async global->LDS, 16B per lane; lds base must be wave-uniform (HW adds lane*16)
__device__ __forceinline__ void gload_lds16(const unsigned short* g, unsigned short* l) {
  __builtin_amdgcn_global_load_lds(
      (const __attribute__((address_space(1))) void*)g,
      (__attribute__((address_space(3))) void*)l, 16, 0, 0);
}

// ---------------- fused fp32->bf16 convert (x, Wqkv, Wo) + vT halo zero ----------------
#define XQ 1048576
#define WQKVQ 786432
#define WOQ 262144
#define CVTQ (XQ + WQKVQ + WOQ)      // 2,097,152 quads
__global__ __launch_bounds__(256) void cvt3_kernel(
    const float* __restrict__ x, const float* __restrict__ wqkv, const float* __restrict__ wo,
    unsigned short* __restrict__ xb, unsigned short* __restrict__ wqkvb, unsigned short* __restrict__ wob,
    unsigned short* __restrict__ vTp) {
  int i = blockIdx.x * blockDim.x + threadIdx.x;
  if (i < CVTQ) {
    const float* s; unsigned short* d; int off;
    if (i < XQ)               { s = x;    d = xb;    off = i; }
    else if (i < XQ + WQKVQ)  { s = wqkv; d = wqkvb; off = i - XQ; }
    else                      { s = wo;   d = wob;   off = i - XQ - WQKVQ; }
    float4 f = reinterpret_cast<const float4*>(s)[off];
    ushort4 o;
    o.x = f2bf(f.x); o.y = f2bf(f.y); o.z = f2bf(f.z); o.w = f2bf(f.w);
    reinterpret_cast<ushort4*>(d)[off] = o;
  } else {
    int j = i - CVTQ;                      // 0..147455
    int row = j / 72, p = j % 72;          // row = bh*64+d
    int off = row * 584 + (p < 32 ? p : 544 + (p - 32));  // left 128 u16 / right 160 u16
    reinterpret_cast<ushort4*>(vTp)[off] = (ushort4){0, 0, 0, 0};
  }
}

// ---------------- QKV GEMM: 64x192 head-aligned tiles, BK=64 dual slab ----------------
// nb = head (0..15), tile cols = exactly [q 0..63 | k 64..127 | v 128..191] of head nb.
// grid 1024 = mb*16+nb -> XCD = nb%8 == attn's bh%8 home XCD (producer/consumer L2 match).
__global__ __launch_bounds__(256) void gemm_qkv(
    const unsigned short* __restrict__ A, const unsigned short* __restrict__ Bm,
    const float* __restrict__ bias, const int* __restrict__ pm,
    unsigned short* __restrict__ qo, unsigned short* __restrict__ ko,
    unsigned short* __restrict__ vTp)
{
  // staging: As[2][64][32] (4096 u16) + Bs[2][192][32] (12288 u16) = 32 KB
  // epilogue reuse: Cld[64][CLP2] = 12800 u16 (25.6 KB)
  __shared__ __align__(16) unsigned short smem[16384];
  unsigned short* As = smem;
  unsigned short* Bs = smem + 4096;
  const int t = threadIdx.x, wave = t >> 6, lane = t & 63;
  const int m16 = lane & 15, q4 = lane >> 4;
  const int wm = wave >> 1, wn = wave & 1;          // 2x2 waves, each 32 rows x 96 cols
  const int bid = blockIdx.x;
  const int mb = bid >> 4, nb = bid & 15;           // nb = head; XCD = nb%8
  const int srow = lane >> 2, scol = (lane & 3) << 3;
  const unsigned short* pA = A + (size_t)(mb * 64 + wave * 16 + srow) * KDIM + scol;
  const unsigned short* pB0 = Bm + (size_t)(nb * 192 + wave * 48 + srow) * KDIM + scol;
  const unsigned short* pB1 = Bm + (size_t)(nb * 192 + wave * 48 + 16 + srow) * KDIM + scol;
  const unsigned short* pB2 = Bm + (size_t)(nb * 192 + wave * 48 + 32 + srow) * KDIM + scol;
  f32x4 acc[2][6];
#pragma unroll
  for (int i_ = 0; i_ < 2; i_++)
#pragma unroll
    for (int j_ = 0; j_ < 6; j_++) acc[i_][j_] = (f32x4){0.f, 0.f, 0.f, 0.f};

  for (int kt = 0; kt < KDIM; kt += 64) {
    __syncthreads();
#pragma unroll
    for (int h = 0; h < 2; h++) {
      gload_lds16(pA + kt + h * 32,  As + h * 2048 + (wave * 16) * 32);
      gload_lds16(pB0 + kt + h * 32, Bs + h * 6144 + (wave * 48) * 32);
      gload_lds16(pB1 + kt + h * 32, Bs + h * 6144 + (wave * 48 + 16) * 32);
      gload_lds16(pB2 + kt + h * 32, Bs + h * 6144 + (wave * 48 + 32) * 32);
    }
    __syncthreads();
#pragma unroll
    for (int h = 0; h < 2; h++) {
      short8 af[2], bf[6];
#pragma unroll
      for (int mt = 0; mt < 2; mt++)
        af[mt] = *reinterpret_cast<const short8*>(&As[h * 2048 + (wm * 32 + mt * 16 + m16) * 32 + q4 * 8]);
#pragma unroll
      for (int nt = 0; nt < 6; nt++)
        bf[nt] = *reinterpret_cast<const short8*>(&Bs[h * 6144 + (wn * 96 + nt * 16 + m16) * 32 + q4 * 8]);
#pragma unroll
      for (int mt = 0; mt < 2; mt++)
#pragma unroll
        for (int nt = 0; nt < 6; nt++)
          acc[mt][nt] = __builtin_amdgcn_mfma_f32_16x16x32_bf16(af[mt], bf[nt], acc[mt][nt], 0, 0, 0);
    }
  }

  __syncthreads();   // frag reads done before smem reuse as Cld
  float pmv[2][4];
#pragma unroll
  for (int mt = 0; mt < 2; mt++)
#pragma unroll
    for (int reg = 0; reg < 4; reg++) {
      int row = mb * 64 + wm * 32 + mt * 16 + q4 * 4 + reg;
      pmv[mt][reg] = (pm[row] != 0) ? 0.0f : 1.0f;
    }
#pragma unroll
  for (int nt = 0; nt < 6; nt++) {
    int cloc = wn * 96 + nt * 16 + m16;
    float bv = bias[nb * 192 + cloc];
#pragma unroll
    for (int mt = 0; mt < 2; mt++) {
#pragma unroll
      for (int reg = 0; reg < 4; reg++) {
        int rloc = wm * 32 + mt * 16 + q4 * 4 + reg;
        smem[rloc * CLP2 + cloc] = f2bf((acc[mt][nt][reg] + bv) * pmv[mt][reg]);
      }
    }
  }
  __syncthreads();
  const int s0 = mb * 64;
  const int bh = (s0 >> 11) * 16 + nb, s0l = s0 & 2047;
  // q/k writeout: thread -> (row r, 16-col seg): 32 B q + 32 B k, full 128B lines
  {
    int r = t >> 2, seg = t & 3;
    const unsigned short* sq = &smem[r * CLP2 + seg * 16];
    unsigned short* dq = qo + ((size_t)(bh * 2048 + s0l + r)) * 64 + seg * 16;
    *reinterpret_cast<short8*>(dq)     = *reinterpret_cast<const short8*>(sq);
    *reinterpret_cast<short8*>(dq + 8) = *reinterpret_cast<const short8*>(sq + 8);
    const unsigned short* sk = &smem[r * CLP2 + 64 + seg * 16];
    unsigned short* dk = ko + ((size_t)(bh * 2048 + s0l + r)) * 64 + seg * 16;
    *reinterpret_cast<short8*>(dk)     = *reinterpret_cast<const short8*>(sk);
    *reinterpret_cast<short8*>(dk + 8) = *reinterpret_cast<const short8*>(sk + 8);
  }
  // vT writeout: thread -> (d = t&63, 16-row quarter): 32 B contiguous in s
  {
    int d = t & 63, qtr = t >> 6;
    short8 tmp0, tmp1;
#pragma unroll
    for (int jj = 0; jj < 8; jj++) {
      tmp0[jj] = (short)smem[(qtr * 16 + jj) * CLP2 + 128 + d];
      tmp1[jj] = (short)smem[(qtr * 16 + 8 + jj) * CLP2 + 128 + d];
    }
    unsigned short* dst = vTp + (size_t)(bh * 64 + d) * SP + 128 + s0l + qtr * 16;
    *reinterpret_cast<short8*>(dst)     = tmp0;
    *reinterpret_cast<short8*>(dst + 8) = tmp1;
  }
}

// ---------------- output projection: 64x64 tile, BK=64, LDS fp32 epilogue ----------------
__global__ __launch_bounds__(256) void gemm_out(
    const unsigned short* __restrict__ A, const unsigned short* __restrict__ Bm,
    const float* __restrict__ bias, float* __restrict__ out)
{
  __shared__ __align__(16) unsigned char smemraw[17408];
  unsigned short* As = (unsigned short*)smemraw;          // 2 slabs x 64x32 (8,192 B)
  unsigned short* Bs = As + 4096;                         // 2 slabs x 64x32 (8,192 B)
  float* Cldf = (float*)smemraw;                          // epilogue: [64][68]
  const int t = threadIdx.x, wave = t >> 6, lane = t & 63;
  const int m16 = lane & 15, q4 = lane >> 4;
  const int wm = wave >> 1, wn = wave & 1;                // 2x2 waves over 64x64 (32x32 each)
  const int flat = blockIdx.y * 16 + blockIdx.x;
  const int xcd = flat & 7, bi = flat >> 3;
  const int mb = xcd * 8 + (bi & 7);                      // per XCD: 8 mb x 16 nb (A 1MB + B 2MB)
  const int nb = bi >> 3;
  const int srow = lane >> 2, scol = (lane & 3) << 3;
  const unsigned short* pA = A + (size_t)(mb * 64 + wave * 16 + srow) * KDIM + scol;
  const unsigned short* pB = Bm + (size_t)(nb * 64 + wave * 16 + srow) * KDIM + scol;
  f32x4 acc[2][2];
#pragma unroll
  for (int i_ = 0; i_ < 2; i_++)
#pragma unroll
    for (int j_ = 0; j_ < 2; j_++) acc[i_][j_] = (f32x4){0.f, 0.f, 0.f, 0.f};
  for (int kt = 0; kt < KDIM; kt += 64) {
    __syncthreads();
#pragma unroll
    for (int h = 0; h < 2; h++) {
      gload_lds16(pA + kt + h * 32, As + h * 2048 + (wave * 16) * 32);
      gload_lds16(pB + kt + h * 32, Bs + h * 2048 + (wave * 16) * 32);
    }
    __syncthreads();
#pragma unroll
    for (int h = 0; h < 2; h++) {
      short8 af[2], bf[2];
#pragma unroll
      for (int mt = 0; mt < 2; mt++)
        af[mt] = *reinterpret_cast<const short8*>(&As[h * 2048 + (wm * 32 + mt * 16 + m16) * 32 + q4 * 8]);
#pragma unroll
      for (int nt = 0; nt < 2; nt++)
        bf[nt] = *reinterpret_cast<const short8*>(&Bs[h * 2048 + (wn * 32 + nt * 16 + m16) * 32 + q4 * 8]);
#pragma unroll
      for (int mt = 0; mt < 2; mt++)
#pragma unroll
        for (int nt = 0; nt < 2; nt++)
          acc[mt][nt] = __builtin_amdgcn_mfma_f32_16x16x32_bf16(af[mt], bf[nt], acc[mt][nt], 0, 0, 0);
    }
  }
  __syncthreads();
#pragma unroll
  for (int nt = 0; nt < 2; nt++) {
    int cloc = wn * 32 + nt * 16 + m16;
    float bv = bias[nb * 64 + cloc];
#pragma unroll
    for (int mt = 0; mt < 2; mt++) {
#pragma unroll
      for (int reg = 0; reg < 4; reg++) {
        int rloc = wm * 32 + mt * 16 + q4 * 4 + reg;
        Cldf[rloc * 68 + cloc] = acc[mt][nt][reg] + bv;
      }
    }
  }
  __syncthreads();
  {
    int r = t >> 2, seg = t & 3;   // 64 rows x 4 segments of 16 floats (64B)
    float* dst = out + (size_t)(mb * 64 + r) * EMBED + nb * 64 + seg * 16;
    const float* srcl = &Cldf[r * 68 + seg * 16];
#pragma unroll
    for (int j = 0; j < 4; j++)
      *reinterpret_cast<float4*>(dst + j * 4) = *reinterpret_cast<const float4*>(srcl + j * 4);
  }
}

// ---------------- banded attention: streaming softmax + dead-chunk skip ----------------
__global__ __launch_bounds__(256, 4) void attn_kernel(
    const unsigned short* __restrict__ q, const unsigned short* __restrict__ k,
    const unsigned short* __restrict__ vTp, unsigned short* __restrict__ vals)
{
  __shared__ __align__(16) unsigned short Pld[4][16][296]; // 37,888 B -> 4 blocks/CU
  const int bid = blockIdx.x;
  const int bh = bid & 31, qtg = bid >> 5;                 // bh-fastest: XCD bh%8 owns its K/V
  const int lane = threadIdx.x & 63, wave = threadIdx.x >> 6;
  const int qt = qtg * 4 + wave;
  const int i0 = qt * 16, w0 = i0 - 128;
  const int m16 = lane & 15, q4 = lane >> 4;

  const unsigned short* qb = q + ((size_t)(bh * 2048 + i0 + m16)) * 64 + q4 * 8;
  short8 aq0 = *reinterpret_cast<const short8*>(qb);
  short8 aq1 = *reinterpret_cast<const short8*>(qb + 32);

  float sum[4] = {0.f, 0.f, 0.f, 0.f};
#pragma unroll
  for (int ct = 0; ct < 18; ct++) {
    // band union for a 16-row tile = 272 cols -> ct=17 always dead
    bool live = (ct < 17) && (w0 + ct * 16 + 15 >= 0) && (w0 + ct * 16 < 2048);
    if (live) {
      int js = w0 + ct * 16 + m16;
      int jc = js < 0 ? 0 : (js > 2047 ? 2047 : js);
      const unsigned short* kb = k + ((size_t)(bh * 2048 + jc)) * 64 + q4 * 8;
      short8 b0 = *reinterpret_cast<const short8*>(kb);
      short8 b1 = *reinterpret_cast<const short8*>(kb + 32);
      f32x4 a = {0.f, 0.f, 0.f, 0.f};
      a = __builtin_amdgcn_mfma_f32_16x16x32_bf16(aq0, b0, a, 0, 0, 0);
      a = __builtin_amdgcn_mfma_f32_16x16x32_bf16(aq1, b1, a, 0, 0, 0);
#pragma unroll
      for (int reg = 0; reg < 4; reg++) {
        int i = i0 + q4 * 4 + reg;
        bool valid = (js >= 0) && (js < 2048) && (js >= i - 128) && (js <= i + 128);
        float e = valid ? __expf(a[reg] * 0.125f) : 0.0f;
        sum[reg] += e;
        Pld[wave][q4 * 4 + reg][ct * 16 + m16] = f2bf(e);
      }
    } else {
#pragma unroll
      for (int reg = 0; reg < 4; reg++)
        Pld[wave][q4 * 4 + reg][ct * 16 + m16] = 0;
    }
  }
  float rden[4];
#pragma unroll
  for (int reg = 0; reg < 4; reg++) {
    float s = sum[reg];
    s += __shfl_xor(s, 1);
    s += __shfl_xor(s, 2);
    s += __shfl_xor(s, 4);
    s += __shfl_xor(s, 8);
    rden[reg] = 1.0f / s;
  }
  __syncthreads();
  short8 ap[9];
#pragma unroll
  for (int kc = 0; kc < 9; kc++)
    ap[kc] = *reinterpret_cast<const short8*>(&Pld[wave][m16][kc * 32 + q4 * 8]);

  const int b = bh >> 4, h = bh & 15;
#pragma unroll
  for (int dt = 0; dt < 4; dt++) {
    f32x4 av = {0.f, 0.f, 0.f, 0.f};
    const unsigned short* vb = vTp + ((size_t)(bh * 64 + dt * 16 + m16)) * SP + i0 + q4 * 8;
#pragma unroll
    for (int kc = 0; kc < 9; kc++) {
      short8 bv = *reinterpret_cast<const short8*>(vb + kc * 32);
      av = __builtin_amdgcn_mfma_f32_16x16x32_bf16(ap[kc], bv, av, 0, 0, 0);
    }
#pragma unroll
    for (int reg = 0; reg < 4; reg++)
      Pld[wave][q4 * 4 + reg][dt * 16 + m16] = f2bf(av[reg] * rden[reg]);
  }
  // coalesced O writeout: 4 lanes x 32B per row -> full 128B lines
  {
    int srow = lane >> 2, seg = lane & 3;
    unsigned short* dst = vals + ((size_t)(b * 2048 + i0 + srow)) * 1024 + h * 64 + seg * 16;
    const unsigned short* srcl = &Pld[wave][srow][seg * 16];
    *reinterpret_cast<short8*>(dst)     = *reinterpret_cast<const short8*>(srcl);
    *reinterpret_cast<short8*>(dst + 8) = *reinterpret_cast<const short8*>(srcl + 8);
  }
}

extern "C" void kernel_launch(void* const* d_in, const int* in_sizes, int n_in,
                              void* d_out, int out_size, void* d_ws, size_t ws_size,
                              hipStream_t stream) {
  const float* x    = (const float*)d_in[0];
  const int*   pm   = (const int*)d_in[1];
  const float* Wqkv = (const float*)d_in[2];
  const float* bqkv = (const float*)d_in[3];
  const float* Wo   = (const float*)d_in[4];
  const float* bo   = (const float*)d_in[5];
  float* out = (float*)d_out;
  char* ws = (char*)d_ws;

  unsigned short* xb    = (unsigned short*)(ws);                 //  8,388,608
  unsigned short* vals  = (unsigned short*)(ws);                 //  reuse (xb dead after gemm_qkv)
  unsigned short* Wqkvb = (unsigned short*)(ws +  8388608);      //  6,291,456
  unsigned short* Wob   = (unsigned short*)(ws + 14680064);      //  2,097,152
  unsigned short* qbuf  = (unsigned short*)(ws + 16777216);      //  8,388,608
  unsigned short* kbuf  = (unsigned short*)(ws + 25165824);      //  8,388,608
  unsigned short* vTp   = (unsigned short*)(ws + 33554432);      //  9,568,256 (ends 43,122,688)

  cvt3_kernel<<<8768, 256, 0, stream>>>(x, Wqkv, Wo, xb, Wqkvb, Wob, vTp);
  gemm_qkv<<<1024, 256, 0, stream>>>(xb, Wqkvb, bqkv, pm, qbuf, kbuf, vTp);
  attn_kernel<<<1024, 256, 0, stream>>>(qbuf, kbuf, vTp, vals);
  gemm_out<<<dim3(16, 64), 256, 0, stream>>>(vals, Wob, bo, out);
}

// Round 8
// 170.115 us; speedup vs baseline: 1.0757x; 1.0757x over previous
//
#include <hip/hip_runtime.h>
#include <stdint.h>

#define S_LEN 2048
#define EMBED 1024
#define HEADS 16
#define HD 64
#define M_ROWS 4096      // B*S
#define N_QKV 3072
#define KDIM 1024
#define SP 2336          // padded vT row length: 128 + 2048 + 160
#define CLP2 200         // qkv C-tile LDS col stride (u16)

typedef __attribute__((ext_vector_type(8))) short short8;
typedef __attribute__((ext_vector_type(4))) float f32x4;

__device__ __forceinline__ unsigned short f2bf(float f) {
  union { float f; uint32_t u; } c; c.f = f;
  uint32_t u = c.u;
  u += 0x7fffu + ((u >> 16) & 1u);  // round-to-nearest-even
  return (unsigned short)(u >> 16);
}

// async global->LDS, 16B per lane; lds base must be wave-uniform (HW adds lane*16)
__device__ __forceinline__ void gload_lds16(const unsigned short* g, unsigned short* l) {
  __builtin_amdgcn_global_load_lds(
      (const __attribute__((address_space(1))) void*)g,
      (__attribute__((address_space(3))) void*)l, 16, 0, 0);
}

// ---------------- fused fp32->bf16 convert (x, Wqkv, Wo) + vT halo zero ----------------
#define XQ 1048576
#define WQKVQ 786432
#define WOQ 262144
#define CVTQ (XQ + WQKVQ + WOQ)      // 2,097,152 quads
__global__ __launch_bounds__(256) void cvt3_kernel(
    const float* __restrict__ x, const float* __restrict__ wqkv, const float* __restrict__ wo,
    unsigned short* __restrict__ xb, unsigned short* __restrict__ wqkvb, unsigned short* __restrict__ wob,
    unsigned short* __restrict__ vTp) {
  int i = blockIdx.x * blockDim.x + threadIdx.x;
  if (i < CVTQ) {
    const float* s; unsigned short* d; int off;
    if (i < XQ)               { s = x;    d = xb;    off = i; }
    else if (i < XQ + WQKVQ)  { s = wqkv; d = wqkvb; off = i - XQ; }
    else                      { s = wo;   d = wob;   off = i - XQ - WQKVQ; }
    float4 f = reinterpret_cast<const float4*>(s)[off];
    ushort4 o;
    o.x = f2bf(f.x); o.y = f2bf(f.y); o.z = f2bf(f.z); o.w = f2bf(f.w);
    reinterpret_cast<ushort4*>(d)[off] = o;
  } else {
    int j = i - CVTQ;                      // 0..147455
    int row = j / 72, p = j % 72;          // row = bh*64+d
    int off = row * 584 + (p < 32 ? p : 544 + (p - 32));  // left 128 u16 / right 160 u16
    reinterpret_cast<ushort4*>(vTp)[off] = (ushort4){0, 0, 0, 0};
  }
}

// ---------------- QKV GEMM: 64x192 head-aligned tiles, BK=64 dual slab ----------------
__global__ __launch_bounds__(256) void gemm_qkv(
    const unsigned short* __restrict__ A, const unsigned short* __restrict__ Bm,
    const float* __restrict__ bias, const int* __restrict__ pm,
    unsigned short* __restrict__ qo, unsigned short* __restrict__ ko,
    unsigned short* __restrict__ vTp)
{
  __shared__ __align__(16) unsigned short smem[16384];
  unsigned short* As = smem;
  unsigned short* Bs = smem + 4096;
  const int t = threadIdx.x, wave = t >> 6, lane = t & 63;
  const int m16 = lane & 15, q4 = lane >> 4;
  const int wm = wave >> 1, wn = wave & 1;          // 2x2 waves, each 32 rows x 96 cols
  const int bid = blockIdx.x;
  const int mb = bid >> 4, nb = bid & 15;           // nb = head
  const int srow = lane >> 2, scol = (lane & 3) << 3;
  const unsigned short* pA = A + (size_t)(mb * 64 + wave * 16 + srow) * KDIM + scol;
  const unsigned short* pB0 = Bm + (size_t)(nb * 192 + wave * 48 + srow) * KDIM + scol;
  const unsigned short* pB1 = Bm + (size_t)(nb * 192 + wave * 48 + 16 + srow) * KDIM + scol;
  const unsigned short* pB2 = Bm + (size_t)(nb * 192 + wave * 48 + 32 + srow) * KDIM + scol;
  f32x4 acc[2][6];
#pragma unroll
  for (int i_ = 0; i_ < 2; i_++)
#pragma unroll
    for (int j_ = 0; j_ < 6; j_++) acc[i_][j_] = (f32x4){0.f, 0.f, 0.f, 0.f};

  for (int kt = 0; kt < KDIM; kt += 64) {
    __syncthreads();
#pragma unroll
    for (int h = 0; h < 2; h++) {
      gload_lds16(pA + kt + h * 32,  As + h * 2048 + (wave * 16) * 32);
      gload_lds16(pB0 + kt + h * 32, Bs + h * 6144 + (wave * 48) * 32);
      gload_lds16(pB1 + kt + h * 32, Bs + h * 6144 + (wave * 48 + 16) * 32);
      gload_lds16(pB2 + kt + h * 32, Bs + h * 6144 + (wave * 48 + 32) * 32);
    }
    __syncthreads();
#pragma unroll
    for (int h = 0; h < 2; h++) {
      short8 af[2], bf[6];
#pragma unroll
      for (int mt = 0; mt < 2; mt++)
        af[mt] = *reinterpret_cast<const short8*>(&As[h * 2048 + (wm * 32 + mt * 16 + m16) * 32 + q4 * 8]);
#pragma unroll
      for (int nt = 0; nt < 6; nt++)
        bf[nt] = *reinterpret_cast<const short8*>(&Bs[h * 6144 + (wn * 96 + nt * 16 + m16) * 32 + q4 * 8]);
#pragma unroll
      for (int mt = 0; mt < 2; mt++)
#pragma unroll
        for (int nt = 0; nt < 6; nt++)
          acc[mt][nt] = __builtin_amdgcn_mfma_f32_16x16x32_bf16(af[mt], bf[nt], acc[mt][nt], 0, 0, 0);
    }
  }

  __syncthreads();   // frag reads done before smem reuse as Cld
  float pmv[2][4];
#pragma unroll
  for (int mt = 0; mt < 2; mt++)
#pragma unroll
    for (int reg = 0; reg < 4; reg++) {
      int row = mb * 64 + wm * 32 + mt * 16 + q4 * 4 + reg;
      pmv[mt][reg] = (pm[row] != 0) ? 0.0f : 1.0f;
    }
#pragma unroll
  for (int nt = 0; nt < 6; nt++) {
    int cloc = wn * 96 + nt * 16 + m16;
    float bv = bias[nb * 192 + cloc];
#pragma unroll
    for (int mt = 0; mt < 2; mt++) {
#pragma unroll
      for (int reg = 0; reg < 4; reg++) {
        int rloc = wm * 32 + mt * 16 + q4 * 4 + reg;
        smem[rloc * CLP2 + cloc] = f2bf((acc[mt][nt][reg] + bv) * pmv[mt][reg]);
      }
    }
  }
  __syncthreads();
  const int s0 = mb * 64;
  const int bh = (s0 >> 11) * 16 + nb, s0l = s0 & 2047;
  {
    int r = t >> 2, seg = t & 3;
    const unsigned short* sq = &smem[r * CLP2 + seg * 16];
    unsigned short* dq = qo + ((size_t)(bh * 2048 + s0l + r)) * 64 + seg * 16;
    *reinterpret_cast<short8*>(dq)     = *reinterpret_cast<const short8*>(sq);
    *reinterpret_cast<short8*>(dq + 8) = *reinterpret_cast<const short8*>(sq + 8);
    const unsigned short* sk = &smem[r * CLP2 + 64 + seg * 16];
    unsigned short* dk = ko + ((size_t)(bh * 2048 + s0l + r)) * 64 + seg * 16;
    *reinterpret_cast<short8*>(dk)     = *reinterpret_cast<const short8*>(sk);
    *reinterpret_cast<short8*>(dk + 8) = *reinterpret_cast<const short8*>(sk + 8);
  }
  {
    int d = t & 63, qtr = t >> 6;
    short8 tmp0, tmp1;
#pragma unroll
    for (int jj = 0; jj < 8; jj++) {
      tmp0[jj] = (short)smem[(qtr * 16 + jj) * CLP2 + 128 + d];
      tmp1[jj] = (short)smem[(qtr * 16 + 8 + jj) * CLP2 + 128 + d];
    }
    unsigned short* dst = vTp + (size_t)(bh * 64 + d) * SP + 128 + s0l + qtr * 16;
    *reinterpret_cast<short8*>(dst)     = tmp0;
    *reinterpret_cast<short8*>(dst + 8) = tmp1;
  }
}

// ---------------- output projection: 64x64 tile, BK=64, LDS fp32 epilogue ----------------
__global__ __launch_bounds__(256) void gemm_out(
    const unsigned short* __restrict__ A, const unsigned short* __restrict__ Bm,
    const float* __restrict__ bias, float* __restrict__ out)
{
  __shared__ __align__(16) unsigned char smemraw[17408];
  unsigned short* As = (unsigned short*)smemraw;
  unsigned short* Bs = As + 4096;
  float* Cldf = (float*)smemraw;
  const int t = threadIdx.x, wave = t >> 6, lane = t & 63;
  const int m16 = lane & 15, q4 = lane >> 4;
  const int wm = wave >> 1, wn = wave & 1;
  const int flat = blockIdx.y * 16 + blockIdx.x;
  const int xcd = flat & 7, bi = flat >> 3;
  const int mb = xcd * 8 + (bi & 7);
  const int nb = bi >> 3;
  const int srow = lane >> 2, scol = (lane & 3) << 3;
  const unsigned short* pA = A + (size_t)(mb * 64 + wave * 16 + srow) * KDIM + scol;
  const unsigned short* pB = Bm + (size_t)(nb * 64 + wave * 16 + srow) * KDIM + scol;
  f32x4 acc[2][2];
#pragma unroll
  for (int i_ = 0; i_ < 2; i_++)
#pragma unroll
    for (int j_ = 0; j_ < 2; j_++) acc[i_][j_] = (f32x4){0.f, 0.f, 0.f, 0.f};
  for (int kt = 0; kt < KDIM; kt += 64) {
    __syncthreads();
#pragma unroll
    for (int h = 0; h < 2; h++) {
      gload_lds16(pA + kt + h * 32, As + h * 2048 + (wave * 16) * 32);
      gload_lds16(pB + kt + h * 32, Bs + h * 2048 + (wave * 16) * 32);
    }
    __syncthreads();
#pragma unroll
    for (int h = 0; h < 2; h++) {
      short8 af[2], bf[2];
#pragma unroll
      for (int mt = 0; mt < 2; mt++)
        af[mt] = *reinterpret_cast<const short8*>(&As[h * 2048 + (wm * 32 + mt * 16 + m16) * 32 + q4 * 8]);
#pragma unroll
      for (int nt = 0; nt < 2; nt++)
        bf[nt] = *reinterpret_cast<const short8*>(&Bs[h * 2048 + (wn * 32 + nt * 16 + m16) * 32 + q4 * 8]);
#pragma unroll
      for (int mt = 0; mt < 2; mt++)
#pragma unroll
        for (int nt = 0; nt < 2; nt++)
          acc[mt][nt] = __builtin_amdgcn_mfma_f32_16x16x32_bf16(af[mt], bf[nt], acc[mt][nt], 0, 0, 0);
    }
  }
  __syncthreads();
#pragma unroll
  for (int nt = 0; nt < 2; nt++) {
    int cloc = wn * 32 + nt * 16 + m16;
    float bv = bias[nb * 64 + cloc];
#pragma unroll
    for (int mt = 0; mt < 2; mt++) {
#pragma unroll
      for (int reg = 0; reg < 4; reg++) {
        int rloc = wm * 32 + mt * 16 + q4 * 4 + reg;
        Cldf[rloc * 68 + cloc] = acc[mt][nt][reg] + bv;
      }
    }
  }
  __syncthreads();
  {
    int r = t >> 2, seg = t & 3;
    float* dst = out + (size_t)(mb * 64 + r) * EMBED + nb * 64 + seg * 16;
    const float* srcl = &Cldf[r * 68 + seg * 16];
#pragma unroll
    for (int j = 0; j < 4; j++)
      *reinterpret_cast<float4*>(dst + j * 4) = *reinterpret_cast<const float4*>(srcl + j * 4);
  }
}

// ---------------- banded attention v3: bulk LDS staging, branch-free ----------------
// Block = (bh, 64-query group). Stage K window [i0b-128, i0b+192) as Ks[320][64]
// and V^T window as Vs[64][320] via global_load_lds (XOR-swizzled segs, <=2-way banks).
// P carried packed in VGPRs; Pld aliases Ks after one barrier. LDS = 80 KB -> 2 blocks/CU.
__global__ __launch_bounds__(256, 2) void attn_kernel(
    const unsigned short* __restrict__ q, const unsigned short* __restrict__ k,
    const unsigned short* __restrict__ vTp, unsigned short* __restrict__ vals)
{
  __shared__ __align__(16) unsigned short smem[40960];   // 81,920 B
  unsigned short* Ks = smem;            // [320][64] u16 (40,960 B)
  unsigned short* Vs = smem + 20480;    // [64][320] u16 (40,960 B)
  unsigned short* Pld = smem;           // alias over Ks after QK phase: [4][16][296]

  const int bid = blockIdx.x;
  const int bh = bid & 31, qg = bid >> 5;                // bh-fastest: XCD-local K/V
  const int lane = threadIdx.x & 63, wave = threadIdx.x >> 6;
  const int i0b = qg * 64;
  const int i0 = i0b + wave * 16;
  const int m16 = lane & 15, q4 = lane >> 4;

  // ---- stage K window: 40 KB = 40 wave-issues of 1 KB (10 per wave) ----
  const unsigned short* kbase = k + (size_t)bh * 2048 * 64;
#pragma unroll
  for (int n = 0; n < 10; n++) {
    int idx = (n * 4 + wave) * 64 + lane;      // 0..2559
    int krow = idx >> 3, seg = idx & 7;
    int grow = i0b - 128 + krow;
    grow = grow < 0 ? 0 : (grow > 2047 ? 2047 : grow);
    int lseg = seg ^ (krow & 7);               // store swizzled within 128B row
    gload_lds16(kbase + (size_t)grow * 64 + lseg * 8, Ks + (n * 4 + wave) * 512);
  }
  // ---- stage V^T window: 40 KB, rows of 320 u16 (40 segs of 16B) ----
  const unsigned short* vbase = vTp + (size_t)bh * 64 * SP + i0b;  // col(i0b) == key i0b-128
#pragma unroll
  for (int n = 0; n < 10; n++) {
    int idx = (n * 4 + wave) * 64 + lane;      // 0..2559
    int vrow = idx / 40, rem = idx % 40;
    int l = (rem & ~7) | ((rem & 7) ^ (vrow & 7));
    gload_lds16(vbase + (size_t)vrow * SP + l * 8, Vs + (n * 4 + wave) * 512);
  }

  // q fragments (direct, tiny)
  const unsigned short* qb = q + ((size_t)(bh * 2048 + i0 + m16)) * 64 + q4 * 8;
  short8 aq0 = *reinterpret_cast<const short8*>(qb);
  short8 aq1 = *reinterpret_cast<const short8*>(qb + 32);

  __syncthreads();

  // ---- QK^T + streaming exp, P packed in registers ----
  float sum[4] = {0.f, 0.f, 0.f, 0.f};
  uint32_t pP[18][2];
#pragma unroll
  for (int ct = 0; ct < 18; ct++) {
    int r = (wave + ct) * 16 + m16;            // LDS key row (may run past 320: finite data, masked)
    int js = i0b - 128 + r;                    // global key index
    const unsigned short* kr = Ks + r * 64;
    short8 b0 = *reinterpret_cast<const short8*>(kr + ((q4 ^ (r & 7)) * 8));
    short8 b1 = *reinterpret_cast<const short8*>(kr + (((q4 + 4) ^ (r & 7)) * 8));
    f32x4 a = {0.f, 0.f, 0.f, 0.f};
    a = __builtin_amdgcn_mfma_f32_16x16x32_bf16(aq0, b0, a, 0, 0, 0);
    a = __builtin_amdgcn_mfma_f32_16x16x32_bf16(aq1, b1, a, 0, 0, 0);
    unsigned short pe[4];
#pragma unroll
    for (int reg = 0; reg < 4; reg++) {
      int i = i0 + q4 * 4 + reg;
      bool valid = (js >= 0) && (js < 2048) && (js >= i - 128) && (js <= i + 128);
      float e = valid ? __expf(a[reg] * 0.125f) : 0.0f;
      sum[reg] += e;
      pe[reg] = f2bf(e);
    }
    pP[ct][0] = (uint32_t)pe[0] | ((uint32_t)pe[1] << 16);
    pP[ct][1] = (uint32_t)pe[2] | ((uint32_t)pe[3] << 16);
  }
  float rden[4];
#pragma unroll
  for (int reg = 0; reg < 4; reg++) {
    float s = sum[reg];
    s += __shfl_xor(s, 1);
    s += __shfl_xor(s, 2);
    s += __shfl_xor(s, 4);
    s += __shfl_xor(s, 8);
    rden[reg] = 1.0f / s;
  }

  __syncthreads();   // all Ks reads done; Pld may now overwrite Ks

  unsigned short* Pw = Pld + wave * 16 * 296;
#pragma unroll
  for (int ct = 0; ct < 18; ct++) {
    Pw[(q4 * 4 + 0) * 296 + ct * 16 + m16] = (unsigned short)(pP[ct][0] & 0xFFFF);
    Pw[(q4 * 4 + 1) * 296 + ct * 16 + m16] = (unsigned short)(pP[ct][0] >> 16);
    Pw[(q4 * 4 + 2) * 296 + ct * 16 + m16] = (unsigned short)(pP[ct][1] & 0xFFFF);
    Pw[(q4 * 4 + 3) * 296 + ct * 16 + m16] = (unsigned short)(pP[ct][1] >> 16);
  }
  // own-wave LDS ordering handled by lgkmcnt; no block barrier needed
  short8 ap[9];
#pragma unroll
  for (int kc = 0; kc < 9; kc++)
    ap[kc] = *reinterpret_cast<const short8*>(&Pw[m16 * 296 + kc * 32 + q4 * 8]);

  const int b = bh >> 4, h = bh & 15;
#pragma unroll
  for (int dt = 0; dt < 4; dt++) {
    int vrow = dt * 16 + m16;
    const unsigned short* vr = Vs + vrow * 320;
    f32x4 av = {0.f, 0.f, 0.f, 0.f};
#pragma unroll
    for (int kc = 0; kc < 9; kc++) {
      int jseg = kc * 4 + wave * 2 + q4;       // logical 16B seg within V^T row
      if (jseg > 39) jseg = 39;                // clamp: clamped segs have P==0
      int sseg = (jseg & ~7) | ((jseg & 7) ^ (vrow & 7));
      short8 bv = *reinterpret_cast<const short8*>(vr + sseg * 8);
      av = __builtin_amdgcn_mfma_f32_16x16x32_bf16(ap[kc], bv, av, 0, 0, 0);
    }
#pragma unroll
    for (int reg = 0; reg < 4; reg++)
      Pw[(q4 * 4 + reg) * 296 + dt * 16 + m16] = f2bf(av[reg] * rden[reg]);
  }
  // coalesced O writeout: 4 lanes x 32B per row -> full 128B lines
  {
    int srow = lane >> 2, seg = lane & 3;
    unsigned short* dst = vals + ((size_t)(b * 2048 + i0 + srow)) * 1024 + h * 64 + seg * 16;
    const unsigned short* srcl = &Pw[srow * 296 + seg * 16];
    *reinterpret_cast<short8*>(dst)     = *reinterpret_cast<const short8*>(srcl);
    *reinterpret_cast<short8*>(dst + 8) = *reinterpret_cast<const short8*>(srcl + 8);
  }
}

extern "C" void kernel_launch(void* const* d_in, const int* in_sizes, int n_in,
                              void* d_out, int out_size, void* d_ws, size_t ws_size,
                              hipStream_t stream) {
  const float* x    = (const float*)d_in[0];
  const int*   pm   = (const int*)d_in[1];
  const float* Wqkv = (const float*)d_in[2];
  const float* bqkv = (const float*)d_in[3];
  const float* Wo   = (const float*)d_in[4];
  const float* bo   = (const float*)d_in[5];
  float* out = (float*)d_out;
  char* ws = (char*)d_ws;

  unsigned short* xb    = (unsigned short*)(ws);                 //  8,388,608
  unsigned short* vals  = (unsigned short*)(ws);                 //  reuse (xb dead after gemm_qkv)
  unsigned short* Wqkvb = (unsigned short*)(ws +  8388608);      //  6,291,456
  unsigned short* Wob   = (unsigned short*)(ws + 14680064);      //  2,097,152
  unsigned short* qbuf  = (unsigned short*)(ws + 16777216);      //  8,388,608
  unsigned short* kbuf  = (unsigned short*)(ws + 25165824);      //  8,388,608
  unsigned short* vTp   = (unsigned short*)(ws + 33554432);      //  9,568,256 (ends 43,122,688)

  cvt3_kernel<<<8768, 256, 0, stream>>>(x, Wqkv, Wo, xb, Wqkvb, Wob, vTp);
  gemm_qkv<<<1024, 256, 0, stream>>>(xb, Wqkvb, bqkv, pm, qbuf, kbuf, vTp);
  attn_kernel<<<1024, 256, 0, stream>>>(qbuf, kbuf, vTp, vals);
  gemm_out<<<dim3(16, 64), 256, 0, stream>>>(vals, Wob, bo, out);
}

// Round 9
// 167.749 us; speedup vs baseline: 1.0909x; 1.0141x over previous
//
#include <hip/hip_runtime.h>
#include <stdint.h>

#define S_LEN 2048
#define EMBED 1024
#define HEADS 16
#define HD 64
#define M_ROWS 4096      // B*S
#define N_QKV 3072
#define KDIM 1024
#define SP 2336          // padded vT row length: 128 + 2048 + 160
#define CLP2 200         // qkv C-tile LDS col stride (u16)

typedef __attribute__((ext_vector_type(8))) short short8;
typedef __attribute__((ext_vector_type(4))) float f32x4;

__device__ __forceinline__ unsigned short f2bf(float f) {
  union { float f; uint32_t u; } c; c.f = f;
  uint32_t u = c.u;
  u += 0x7fffu + ((u >> 16) & 1u);  // round-to-nearest-even
  return (unsigned short)(u >> 16);
}

// async global->LDS, 16B per lane; lds base must be wave-uniform (HW adds lane*16)
__device__ __forceinline__ void gload_lds16(const unsigned short* g, unsigned short* l) {
  __builtin_amdgcn_global_load_lds(
      (const __attribute__((address_space(1))) void*)g,
      (__attribute__((address_space(3))) void*)l, 16, 0, 0);
}

// ---------------- fused fp32->bf16 convert (x, Wqkv, Wo) + vT halo zero ----------------
#define XQ 1048576
#define WQKVQ 786432
#define WOQ 262144
#define CVTQ (XQ + WQKVQ + WOQ)      // 2,097,152 quads
__global__ __launch_bounds__(256) void cvt3_kernel(
    const float* __restrict__ x, const float* __restrict__ wqkv, const float* __restrict__ wo,
    unsigned short* __restrict__ xb, unsigned short* __restrict__ wqkvb, unsigned short* __restrict__ wob,
    unsigned short* __restrict__ vTp) {
  int i = blockIdx.x * blockDim.x + threadIdx.x;
  if (i < CVTQ) {
    const float* s; unsigned short* d; int off;
    if (i < XQ)               { s = x;    d = xb;    off = i; }
    else if (i < XQ + WQKVQ)  { s = wqkv; d = wqkvb; off = i - XQ; }
    else                      { s = wo;   d = wob;   off = i - XQ - WQKVQ; }
    float4 f = reinterpret_cast<const float4*>(s)[off];
    ushort4 o;
    o.x = f2bf(f.x); o.y = f2bf(f.y); o.z = f2bf(f.z); o.w = f2bf(f.w);
    reinterpret_cast<ushort4*>(d)[off] = o;
  } else {
    int j = i - CVTQ;                      // 0..147455
    int row = j / 72, p = j % 72;          // row = bh*64+d
    int off = row * 584 + (p < 32 ? p : 544 + (p - 32));  // left 128 u16 / right 160 u16
    reinterpret_cast<ushort4*>(vTp)[off] = (ushort4){0, 0, 0, 0};
  }
}

// ---------------- QKV GEMM: 128x192 head-aligned tiles, BK=64 dual slab ----------------
// nb = head (0..15): cols = [q 0..63 | k 64..127 | v 128..191] of head nb.
// 512 blocks, bid%8 = nb%8 -> head's home XCD matches attn's bh%8 swizzle.
// 24 MFMA per 5 staging loads per wave per slab (vs 12:4 at 64x192).
__global__ __launch_bounds__(256) void gemm_qkv(
    const unsigned short* __restrict__ A, const unsigned short* __restrict__ Bm,
    const float* __restrict__ bias, const int* __restrict__ pm,
    unsigned short* __restrict__ qo, unsigned short* __restrict__ ko,
    unsigned short* __restrict__ vTp)
{
  // staging: As 2x128x32 (8192 u16) + Bs 2x192x32 (12288 u16) = 40 KB
  // epilogue reuse: Cld[128][CLP2] = 25600 u16 = 51.2 KB
  __shared__ __align__(16) unsigned short smem[25600];
  unsigned short* As = smem;
  unsigned short* Bs = smem + 8192;
  const int t = threadIdx.x, wave = t >> 6, lane = t & 63;
  const int m16 = lane & 15, q4 = lane >> 4;
  const int wm = wave >> 1, wn = wave & 1;          // 2x2 waves, each 64 rows x 96 cols
  const int bid = blockIdx.x;
  const int mb = bid >> 4, nb = bid & 15;           // nb = head; XCD = nb%8
  const int srow = lane >> 2, scol = (lane & 3) << 3;
  const unsigned short* pA0 = A + (size_t)(mb * 128 + wave * 32 + srow) * KDIM + scol;
  const unsigned short* pA1 = pA0 + 16 * KDIM;
  const unsigned short* pB0 = Bm + (size_t)(nb * 192 + wave * 48 + srow) * KDIM + scol;
  const unsigned short* pB1 = pB0 + 16 * KDIM;
  const unsigned short* pB2 = pB0 + 32 * KDIM;
  f32x4 acc[4][6];
#pragma unroll
  for (int i_ = 0; i_ < 4; i_++)
#pragma unroll
    for (int j_ = 0; j_ < 6; j_++) acc[i_][j_] = (f32x4){0.f, 0.f, 0.f, 0.f};

  for (int kt = 0; kt < KDIM; kt += 64) {
    __syncthreads();
#pragma unroll
    for (int h = 0; h < 2; h++) {
      gload_lds16(pA0 + kt + h * 32, As + h * 4096 + (wave * 32) * 32);
      gload_lds16(pA1 + kt + h * 32, As + h * 4096 + (wave * 32 + 16) * 32);
      gload_lds16(pB0 + kt + h * 32, Bs + h * 6144 + (wave * 48) * 32);
      gload_lds16(pB1 + kt + h * 32, Bs + h * 6144 + (wave * 48 + 16) * 32);
      gload_lds16(pB2 + kt + h * 32, Bs + h * 6144 + (wave * 48 + 32) * 32);
    }
    __syncthreads();
#pragma unroll
    for (int h = 0; h < 2; h++) {
      short8 af[4], bf[6];
#pragma unroll
      for (int mt = 0; mt < 4; mt++)
        af[mt] = *reinterpret_cast<const short8*>(&As[h * 4096 + (wm * 64 + mt * 16 + m16) * 32 + q4 * 8]);
#pragma unroll
      for (int nt = 0; nt < 6; nt++)
        bf[nt] = *reinterpret_cast<const short8*>(&Bs[h * 6144 + (wn * 96 + nt * 16 + m16) * 32 + q4 * 8]);
#pragma unroll
      for (int mt = 0; mt < 4; mt++)
#pragma unroll
        for (int nt = 0; nt < 6; nt++)
          acc[mt][nt] = __builtin_amdgcn_mfma_f32_16x16x32_bf16(af[mt], bf[nt], acc[mt][nt], 0, 0, 0);
    }
  }

  __syncthreads();   // frag reads done before smem reuse as Cld
  float pmv[4][4];
#pragma unroll
  for (int mt = 0; mt < 4; mt++)
#pragma unroll
    for (int reg = 0; reg < 4; reg++) {
      int row = mb * 128 + wm * 64 + mt * 16 + q4 * 4 + reg;
      pmv[mt][reg] = (pm[row] != 0) ? 0.0f : 1.0f;
    }
#pragma unroll
  for (int nt = 0; nt < 6; nt++) {
    int cloc = wn * 96 + nt * 16 + m16;
    float bv = bias[nb * 192 + cloc];
#pragma unroll
    for (int mt = 0; mt < 4; mt++) {
#pragma unroll
      for (int reg = 0; reg < 4; reg++) {
        int rloc = wm * 64 + mt * 16 + q4 * 4 + reg;
        smem[rloc * CLP2 + cloc] = f2bf((acc[mt][nt][reg] + bv) * pmv[mt][reg]);
      }
    }
  }
  __syncthreads();
  const int s0 = mb * 128;                 // 128-row tiles never cross the 2048 batch boundary
  const int bh = (s0 >> 11) * 16 + nb, s0l = s0 & 2047;
  // q/k writeout: thread -> (row r of 128, 32-col half): 64 B q + 64 B k
  {
    int r = t >> 1, half = t & 1;
    const unsigned short* sq = &smem[r * CLP2 + half * 32];
    unsigned short* dq = qo + ((size_t)(bh * 2048 + s0l + r)) * 64 + half * 32;
#pragma unroll
    for (int j = 0; j < 4; j++)
      *reinterpret_cast<short8*>(dq + j * 8) = *reinterpret_cast<const short8*>(sq + j * 8);
    const unsigned short* sk = &smem[r * CLP2 + 64 + half * 32];
    unsigned short* dk = ko + ((size_t)(bh * 2048 + s0l + r)) * 64 + half * 32;
#pragma unroll
    for (int j = 0; j < 4; j++)
      *reinterpret_cast<short8*>(dk + j * 8) = *reinterpret_cast<const short8*>(sk + j * 8);
  }
  // vT writeout: thread -> (d = t&63, 32-row quarter): 64 B contiguous in s
  {
    int d = t & 63, qtr = t >> 6;
    unsigned short* dst = vTp + (size_t)(bh * 64 + d) * SP + 128 + s0l + qtr * 32;
#pragma unroll
    for (int j8 = 0; j8 < 4; j8++) {
      short8 tmp;
#pragma unroll
      for (int jj = 0; jj < 8; jj++)
        tmp[jj] = (short)smem[(qtr * 32 + j8 * 8 + jj) * CLP2 + 128 + d];
      *reinterpret_cast<short8*>(dst + j8 * 8) = tmp;
    }
  }
}

// ---------------- output projection: 64x128 tile, BK=64, LDS fp32 epilogue ----------------
// 512 blocks = 2/CU.
__global__ __launch_bounds__(256) void gemm_out(
    const unsigned short* __restrict__ A, const unsigned short* __restrict__ Bm,
    const float* __restrict__ bias, float* __restrict__ out)
{
  __shared__ __align__(16) unsigned char smemraw[33792];
  unsigned short* As = (unsigned short*)smemraw;          // 2 slabs x 64x32  (8,192 B)
  unsigned short* Bs = As + 4096;                         // 2 slabs x 128x32 (16,384 B)
  float* Cldf = (float*)smemraw;                          // epilogue: [64][132]
  const int t = threadIdx.x, wave = t >> 6, lane = t & 63;
  const int m16 = lane & 15, q4 = lane >> 4;
  const int wm = wave >> 1, wn = wave & 1;                // 2x2 waves: 32 rows x 64 cols each
  const int flat = blockIdx.y * 8 + blockIdx.x;
  const int xcd = flat & 7, bi = flat >> 3;
  const int mb = xcd * 8 + (bi & 7);                      // per XCD: 8 mb x 8 nb
  const int nb = bi >> 3;
  const int srow = lane >> 2, scol = (lane & 3) << 3;
  const unsigned short* pA  = A + (size_t)(mb * 64 + wave * 16 + srow) * KDIM + scol;
  const unsigned short* pB0 = Bm + (size_t)(nb * 128 + wave * 32 + srow) * KDIM + scol;
  const unsigned short* pB1 = pB0 + 16 * KDIM;
  f32x4 acc[2][4];
#pragma unroll
  for (int i_ = 0; i_ < 2; i_++)
#pragma unroll
    for (int j_ = 0; j_ < 4; j_++) acc[i_][j_] = (f32x4){0.f, 0.f, 0.f, 0.f};
  for (int kt = 0; kt < KDIM; kt += 64) {
    __syncthreads();
#pragma unroll
    for (int h = 0; h < 2; h++) {
      gload_lds16(pA + kt + h * 32,  As + h * 2048 + (wave * 16) * 32);
      gload_lds16(pB0 + kt + h * 32, Bs + h * 4096 + (wave * 32) * 32);
      gload_lds16(pB1 + kt + h * 32, Bs + h * 4096 + (wave * 32 + 16) * 32);
    }
    __syncthreads();
#pragma unroll
    for (int h = 0; h < 2; h++) {
      short8 af[2], bf[4];
#pragma unroll
      for (int mt = 0; mt < 2; mt++)
        af[mt] = *reinterpret_cast<const short8*>(&As[h * 2048 + (wm * 32 + mt * 16 + m16) * 32 + q4 * 8]);
#pragma unroll
      for (int nt = 0; nt < 4; nt++)
        bf[nt] = *reinterpret_cast<const short8*>(&Bs[h * 4096 + (wn * 64 + nt * 16 + m16) * 32 + q4 * 8]);
#pragma unroll
      for (int mt = 0; mt < 2; mt++)
#pragma unroll
        for (int nt = 0; nt < 4; nt++)
          acc[mt][nt] = __builtin_amdgcn_mfma_f32_16x16x32_bf16(af[mt], bf[nt], acc[mt][nt], 0, 0, 0);
    }
  }
  __syncthreads();
#pragma unroll
  for (int nt = 0; nt < 4; nt++) {
    int cloc = wn * 64 + nt * 16 + m16;
    float bv = bias[nb * 128 + cloc];
#pragma unroll
    for (int mt = 0; mt < 2; mt++) {
#pragma unroll
      for (int reg = 0; reg < 4; reg++) {
        int rloc = wm * 32 + mt * 16 + q4 * 4 + reg;
        Cldf[rloc * 132 + cloc] = acc[mt][nt][reg] + bv;
      }
    }
  }
  __syncthreads();
  {
    int r = t >> 2, seg = t & 3;   // 64 rows x 4 segments of 32 floats (128 B)
    float* dst = out + (size_t)(mb * 64 + r) * EMBED + nb * 128 + seg * 32;
    const float* srcl = &Cldf[r * 132 + seg * 32];
#pragma unroll
    for (int j = 0; j < 8; j++)
      *reinterpret_cast<float4*>(dst + j * 4) = *reinterpret_cast<const float4*>(srcl + j * 4);
  }
}

// ---------------- banded attention v3: bulk LDS staging, branch-free ----------------
__global__ __launch_bounds__(256, 2) void attn_kernel(
    const unsigned short* __restrict__ q, const unsigned short* __restrict__ k,
    const unsigned short* __restrict__ vTp, unsigned short* __restrict__ vals)
{
  __shared__ __align__(16) unsigned short smem[40960];   // 81,920 B
  unsigned short* Ks = smem;            // [320][64] u16 (40,960 B)
  unsigned short* Vs = smem + 20480;    // [64][320] u16 (40,960 B)
  unsigned short* Pld = smem;           // alias over Ks after QK phase: [4][16][296]

  const int bid = blockIdx.x;
  const int bh = bid & 31, qg = bid >> 5;                // bh-fastest: XCD-local K/V
  const int lane = threadIdx.x & 63, wave = threadIdx.x >> 6;
  const int i0b = qg * 64;
  const int i0 = i0b + wave * 16;
  const int m16 = lane & 15, q4 = lane >> 4;

  // ---- stage K window: 40 KB = 40 wave-issues of 1 KB (10 per wave) ----
  const unsigned short* kbase = k + (size_t)bh * 2048 * 64;
#pragma unroll
  for (int n = 0; n < 10; n++) {
    int idx = (n * 4 + wave) * 64 + lane;      // 0..2559
    int krow = idx >> 3, seg = idx & 7;
    int grow = i0b - 128 + krow;
    grow = grow < 0 ? 0 : (grow > 2047 ? 2047 : grow);
    int lseg = seg ^ (krow & 7);               // store swizzled within 128B row
    gload_lds16(kbase + (size_t)grow * 64 + lseg * 8, Ks + (n * 4 + wave) * 512);
  }
  // ---- stage V^T window: 40 KB, rows of 320 u16 (40 segs of 16B) ----
  const unsigned short* vbase = vTp + (size_t)bh * 64 * SP + i0b;  // col(i0b) == key i0b-128
#pragma unroll
  for (int n = 0; n < 10; n++) {
    int idx = (n * 4 + wave) * 64 + lane;      // 0..2559
    int vrow = idx / 40, rem = idx % 40;
    int l = (rem & ~7) | ((rem & 7) ^ (vrow & 7));
    gload_lds16(vbase + (size_t)vrow * SP + l * 8, Vs + (n * 4 + wave) * 512);
  }

  // q fragments (direct, tiny)
  const unsigned short* qb = q + ((size_t)(bh * 2048 + i0 + m16)) * 64 + q4 * 8;
  short8 aq0 = *reinterpret_cast<const short8*>(qb);
  short8 aq1 = *reinterpret_cast<const short8*>(qb + 32);

  __syncthreads();

  // ---- QK^T + streaming exp, P packed in registers ----
  float sum[4] = {0.f, 0.f, 0.f, 0.f};
  uint32_t pP[18][2];
#pragma unroll
  for (int ct = 0; ct < 18; ct++) {
    int r = (wave + ct) * 16 + m16;            // LDS key row (may run past 320: finite data, masked)
    int js = i0b - 128 + r;                    // global key index
    const unsigned short* kr = Ks + r * 64;
    short8 b0 = *reinterpret_cast<const short8*>(kr + ((q4 ^ (r & 7)) * 8));
    short8 b1 = *reinterpret_cast<const short8*>(kr + (((q4 + 4) ^ (r & 7)) * 8));
    f32x4 a = {0.f, 0.f, 0.f, 0.f};
    a = __builtin_amdgcn_mfma_f32_16x16x32_bf16(aq0, b0, a, 0, 0, 0);
    a = __builtin_amdgcn_mfma_f32_16x16x32_bf16(aq1, b1, a, 0, 0, 0);
    unsigned short pe[4];
#pragma unroll
    for (int reg = 0; reg < 4; reg++) {
      int i = i0 + q4 * 4 + reg;
      bool valid = (js >= 0) && (js < 2048) && (js >= i - 128) && (js <= i + 128);
      float e = valid ? __expf(a[reg] * 0.125f) : 0.0f;
      sum[reg] += e;
      pe[reg] = f2bf(e);
    }
    pP[ct][0] = (uint32_t)pe[0] | ((uint32_t)pe[1] << 16);
    pP[ct][1] = (uint32_t)pe[2] | ((uint32_t)pe[3] << 16);
  }
  float rden[4];
#pragma unroll
  for (int reg = 0; reg < 4; reg++) {
    float s = sum[reg];
    s += __shfl_xor(s, 1);
    s += __shfl_xor(s, 2);
    s += __shfl_xor(s, 4);
    s += __shfl_xor(s, 8);
    rden[reg] = 1.0f / s;
  }

  __syncthreads();   // all Ks reads done; Pld may now overwrite Ks

  unsigned short* Pw = Pld + wave * 16 * 296;
#pragma unroll
  for (int ct = 0; ct < 18; ct++) {
    Pw[(q4 * 4 + 0) * 296 + ct * 16 + m16] = (unsigned short)(pP[ct][0] & 0xFFFF);
    Pw[(q4 * 4 + 1) * 296 + ct * 16 + m16] = (unsigned short)(pP[ct][0] >> 16);
    Pw[(q4 * 4 + 2) * 296 + ct * 16 + m16] = (unsigned short)(pP[ct][1] & 0xFFFF);
    Pw[(q4 * 4 + 3) * 296 + ct * 16 + m16] = (unsigned short)(pP[ct][1] >> 16);
  }
  // own-wave LDS ordering handled by lgkmcnt; no block barrier needed
  short8 ap[9];
#pragma unroll
  for (int kc = 0; kc < 9; kc++)
    ap[kc] = *reinterpret_cast<const short8*>(&Pw[m16 * 296 + kc * 32 + q4 * 8]);

  const int b = bh >> 4, h = bh & 15;
#pragma unroll
  for (int dt = 0; dt < 4; dt++) {
    int vrow = dt * 16 + m16;
    const unsigned short* vr = Vs + vrow * 320;
    f32x4 av = {0.f, 0.f, 0.f, 0.f};
#pragma unroll
    for (int kc = 0; kc < 9; kc++) {
      int jseg = kc * 4 + wave * 2 + q4;       // logical 16B seg within V^T row
      if (jseg > 39) jseg = 39;                // clamp: clamped segs have P==0
      int sseg = (jseg & ~7) | ((jseg & 7) ^ (vrow & 7));
      short8 bv = *reinterpret_cast<const short8*>(vr + sseg * 8);
      av = __builtin_amdgcn_mfma_f32_16x16x32_bf16(ap[kc], bv, av, 0, 0, 0);
    }
#pragma unroll
    for (int reg = 0; reg < 4; reg++)
      Pw[(q4 * 4 + reg) * 296 + dt * 16 + m16] = f2bf(av[reg] * rden[reg]);
  }
  // coalesced O writeout: 4 lanes x 32B per row -> full 128B lines
  {
    int srow = lane >> 2, seg = lane & 3;
    unsigned short* dst = vals + ((size_t)(b * 2048 + i0 + srow)) * 1024 + h * 64 + seg * 16;
    const unsigned short* srcl = &Pw[srow * 296 + seg * 16];
    *reinterpret_cast<short8*>(dst)     = *reinterpret_cast<const short8*>(srcl);
    *reinterpret_cast<short8*>(dst + 8) = *reinterpret_cast<const short8*>(srcl + 8);
  }
}

extern "C" void kernel_launch(void* const* d_in, const int* in_sizes, int n_in,
                              void* d_out, int out_size, void* d_ws, size_t ws_size,
                              hipStream_t stream) {
  const float* x    = (const float*)d_in[0];
  const int*   pm   = (const int*)d_in[1];
  const float* Wqkv = (const float*)d_in[2];
  const float* bqkv = (const float*)d_in[3];
  const float* Wo   = (const float*)d_in[4];
  const float* bo   = (const float*)d_in[5];
  float* out = (float*)d_out;
  char* ws = (char*)d_ws;

  unsigned short* xb    = (unsigned short*)(ws);                 //  8,388,608
  unsigned short* vals  = (unsigned short*)(ws);                 //  reuse (xb dead after gemm_qkv)
  unsigned short* Wqkvb = (unsigned short*)(ws +  8388608);      //  6,291,456
  unsigned short* Wob   = (unsigned short*)(ws + 14680064);      //  2,097,152
  unsigned short* qbuf  = (unsigned short*)(ws + 16777216);      //  8,388,608
  unsigned short* kbuf  = (unsigned short*)(ws + 25165824);      //  8,388,608
  unsigned short* vTp   = (unsigned short*)(ws + 33554432);      //  9,568,256 (ends 43,122,688)

  cvt3_kernel<<<8768, 256, 0, stream>>>(x, Wqkv, Wo, xb, Wqkvb, Wob, vTp);
  gemm_qkv<<<512, 256, 0, stream>>>(xb, Wqkvb, bqkv, pm, qbuf, kbuf, vTp);
  attn_kernel<<<1024, 256, 0, stream>>>(qbuf, kbuf, vTp, vals);
  gemm_out<<<dim3(8, 64), 256, 0, stream>>>(vals, Wob, bo, out);
}